// Round 7
// baseline (109.587 us; speedup 1.0000x reference)
//
#include <hip/hip_runtime.h>

// CurvatureLoss: B=4, N=4096, fp32.
// R14: R13 (full-async LDS staging) = 53us ~= R7's 51.6 -> latency exposure
// falsified; R7 is genuinely VALU-issue-saturated (96%), and R9's inst cut
// failed only because it exposed stalls. Combine the levers: keep R13's
// latency-tolerant phase-staged structure, cut issued VALU with packed fp32.
// The 6 dots/step = 3 query-pairs; float2 ext-vector + elementwise_fma ->
// v_pk_fma_f32: 18 fma -> 9 pk_fma (-30% per-step VALU). Queries live as 6
// float2 packs (epilogue reloads float4s from L2) -> VGPR stays in envelope.
// Everything else identical to R13 (top-3 + post-collapse, ballot recovery).

constexpr int BB   = 4;
constexpr int NN   = 4096;
constexpr int QPB  = 8;              // queries per block (4 waves x 2)
constexpr int CPB  = 64;             // chunk = lane
constexpr int NK   = NN / CPB;       // 64 steps; candidate j = 64*k + lane
constexpr int PP   = 4;              // steps per phase (= waves per block)
constexpr int NP   = NK / PP;        // 16 phases
constexpr int NBLK = BB * NN / QPB;  // 2048 blocks
constexpr float NEGBIG = -3.402823466e+38f;

typedef float float2v __attribute__((ext_vector_type(2)));

__global__ __launch_bounds__(256) void pack_kernel(
    const float* __restrict__ ori, const float* __restrict__ adv,
    float4* __restrict__ oriP, float4* __restrict__ advP)
{
    const int i = blockIdx.x * blockDim.x + threadIdx.x;
    if (i < BB * NN) {
        float x = ori[3 * i], y = ori[3 * i + 1], z = ori[3 * i + 2];
        oriP[i] = make_float4(x, y, z, 0.5f * (x * x + y * y + z * z));
        x = adv[3 * i]; y = adv[3 * i + 1]; z = adv[3 * i + 2];
        advP[i] = make_float4(x, y, z, 0.5f * (x * x + y * y + z * z));
    }
}

__device__ __forceinline__ float embed6(float t, unsigned eb) {
    return __uint_as_float((__float_as_uint(t) & 0xFFFFFFC0u) | eb);  // v_and_or_b32
}

__device__ __forceinline__ float fmed3(float a, float b, float c) {
    return __builtin_amdgcn_fmed3f(a, b, c);
}

// async global->LDS DMA, 16B per lane; lds dest = wave-uniform base + lane*16
__device__ __forceinline__ void async_copy16(const float4* g, float4* l) {
    __builtin_amdgcn_global_load_lds(
        (const __attribute__((address_space(1))) void*)g,
        (__attribute__((address_space(3))) void*)l, 16, 0, 0);
}

// v: merged key; p0/p1: this lane's (post-collapse) partials. Wave-uniform.
// Lowest matching lane = smallest global index (j = 64k + lane).
__device__ __forceinline__ int recover_j(float v, float p0, float p1) {
    unsigned long long m = __ballot((p0 == v) || (p1 == v));
    const int lane = (int)__ffsll(m) - 1;
    const int k = (NK - 1) - (int)(__float_as_uint(v) & (unsigned)(NK - 1));
    return (k << 6) | lane;
}

__device__ __forceinline__ float unit_absdot4(const float4* __restrict__ pc, int i,
                                              float px, float py, float pz,
                                              float nx, float ny, float nz) {
    const float4 c = pc[i];
    const float vx = c.x - px, vy = c.y - py, vz = c.z - pz;
    const float s  = vx * vx + vy * vy + vz * vz + 1e-12f;
    return fabsf((vx * nx + vy * ny + vz * nz) * (1.0f / sqrtf(s)));
}

__global__ __launch_bounds__(256, 8) void knn_kernel(
    const float4* __restrict__ oriP, const float4* __restrict__ advP,
    const float* __restrict__ nrm, float* __restrict__ partial,
    float* __restrict__ out, int use_partial)
{
    const int tid = threadIdx.x;
    const int ch  = tid & 63;          // chunk = lane
    const int qs  = tid >> 6;          // wave id 0..3
    const int b   = blockIdx.x >> 9;   // / (N/QPB = 512)
    const int qt  = blockIdx.x & 511;
    const int q0  = qt * QPB + qs * 2;
    const int q1  = q0 + 1;

    const float4* __restrict__ ob = oriP + (size_t)b * NN;
    const float4* __restrict__ ab = advP + (size_t)b * NN;
    const float*  __restrict__ nb = nrm  + (size_t)b * NN * 3;

    // queries as packed pairs (w unused in the loop); float4s NOT kept live.
    float2v qox, qoy, qoz, qax, qay, qaz;
    {
        const float4 t0 = ob[q0], t1 = ob[q1];
        qox = (float2v){t0.x, t1.x};
        qoy = (float2v){t0.y, t1.y};
        qoz = (float2v){t0.z, t1.z};
        const float4 u0 = ab[q0], u1 = ab[q1];
        qax = (float2v){u0.x, u1.x};
        qay = (float2v){u0.y, u1.y};
        qaz = (float2v){u0.z, u1.z};
    }

    // top-3 trackers (max = closest); self key is guaranteed rank-1.
    float oA0 = NEGBIG, oB0 = NEGBIG, oC0 = NEGBIG;   // q0 ori-ori
    float oA1 = NEGBIG, oB1 = NEGBIG, oC1 = NEGBIG;   // q1 ori-ori
    float aA0 = NEGBIG, aB0 = NEGBIG, aC0 = NEGBIG;   // q0 adv-adv
    float aA1 = NEGBIG, aB1 = NEGBIG, aC1 = NEGBIG;   // q1 adv-adv
    float m0  = NEGBIG, m1  = NEGBIG;                 // adv->ori argmax

    // phase-staged candidate buffers: [buf][step-in-phase * 64 + cand]
    __shared__ float4 ldsO[2][PP * CPB];
    __shared__ float4 ldsA[2][PP * CPB];

    // wave qs stages step (ph*PP + qs) of phase ph into buffer bf.
    auto stage = [&](int ph, int bf) {
        const int k = ph * PP + qs;
        async_copy16(ob + (size_t)k * CPB + ch, &ldsO[bf][qs * CPB]);
        async_copy16(ab + (size_t)k * CPB + ch, &ldsA[bf][qs * CPB]);
    };

    // one step: 3 packed dot-chains (9 pk_fma) + 6 embed + top-3/argmax
    auto stepf = [&](const float4& co, const float4& ca, unsigned eb) {
        const float2v ncw = {-co.w, -co.w};
        const float2v naw = {-ca.w, -ca.w};
        float2v to, tm, ta;
        to = __builtin_elementwise_fma(qoz, (float2v){co.z, co.z}, ncw);
        to = __builtin_elementwise_fma(qoy, (float2v){co.y, co.y}, to);
        to = __builtin_elementwise_fma(qox, (float2v){co.x, co.x}, to);
        tm = __builtin_elementwise_fma(qaz, (float2v){co.z, co.z}, ncw);
        tm = __builtin_elementwise_fma(qay, (float2v){co.y, co.y}, tm);
        tm = __builtin_elementwise_fma(qax, (float2v){co.x, co.x}, tm);
        ta = __builtin_elementwise_fma(qaz, (float2v){ca.z, ca.z}, naw);
        ta = __builtin_elementwise_fma(qay, (float2v){ca.y, ca.y}, ta);
        ta = __builtin_elementwise_fma(qax, (float2v){ca.x, ca.x}, ta);
        const float ko0 = embed6(to.x, eb);
        const float ko1 = embed6(to.y, eb);
        const float km0 = embed6(tm.x, eb);
        const float km1 = embed6(tm.y, eb);
        const float ka0 = embed6(ta.x, eb);
        const float ka1 = embed6(ta.y, eb);

        // top-3 update, all from OLD values (3-wide ILP):
        oC0 = fmed3(oB0, oC0, ko0); oB0 = fmed3(oA0, oB0, ko0); oA0 = fmaxf(oA0, ko0);
        oC1 = fmed3(oB1, oC1, ko1); oB1 = fmed3(oA1, oB1, ko1); oA1 = fmaxf(oA1, ko1);
        aC0 = fmed3(aB0, aC0, ka0); aB0 = fmed3(aA0, aB0, ka0); aA0 = fmaxf(aA0, ka0);
        aC1 = fmed3(aB1, aC1, ka1); aB1 = fmed3(aA1, aB1, ka1); aA1 = fmaxf(aA1, ka1);
        m0  = fmaxf(m0, km0);
        m1  = fmaxf(m1, km1);
    };

    // prologue: stage phase 0, drain, go.
    stage(0, 0);
    __syncthreads();                   // drains own vmcnt -> buf0 ready

    int cur = 0;
    for (int ph = 0; ph < NP; ++ph) {
        if (ph + 1 < NP) stage(ph + 1, cur ^ 1);   // async, no VGPR results
        const int kb = ph * PP;
        #pragma unroll
        for (int s = 0; s < PP; ++s) {
            const float4 co = ldsO[cur][s * CPB + ch];
            const float4 ca = ldsA[cur][s * CPB + ch];
            stepf(co, ca, (unsigned)(NK - 1 - (kb + s)));
        }
        __syncthreads();               // publishes next buffer (vmcnt drain)
        cur ^= 1;
    }

    // collapse self (guaranteed lane rank-1 in the self lane): drop it, keep 2.
    const bool sq0 = ((q0 & 63) == ch);
    const bool sq1 = ((q1 & 63) == ch);
    oA0 = sq0 ? oB0 : oA0;  oB0 = sq0 ? oC0 : oB0;
    aA0 = sq0 ? aB0 : aA0;  aB0 = sq0 ? aC0 : aB0;
    oA1 = sq1 ? oB1 : oA1;  oB1 = sq1 ? oC1 : oB1;
    aA1 = sq1 ? aB1 : aA1;  aB1 = sq1 ? aC1 : aB1;

    // save per-lane partials for index recovery
    const float soA0 = oA0, soB0 = oB0, soA1 = oA1, soB1 = oB1;
    const float saA0 = aA0, saB0 = aB0, saA1 = aA1, saB1 = aB1;
    const float sm0 = m0, sm1 = m1;

    // wave butterfly top-2 merge: m0=max(a0,b0); m1=max(min(a0,b0),max(a1,b1))
    #pragma unroll
    for (int off = 1; off < 64; off <<= 1) {
        float r0, r1, mn;
        r0 = __shfl_xor(oA0, off); r1 = __shfl_xor(oB0, off);
        mn = fminf(oA0, r0); oA0 = fmaxf(oA0, r0); oB0 = fmaxf(mn, fmaxf(oB0, r1));
        r0 = __shfl_xor(oA1, off); r1 = __shfl_xor(oB1, off);
        mn = fminf(oA1, r0); oA1 = fmaxf(oA1, r0); oB1 = fmaxf(mn, fmaxf(oB1, r1));
        r0 = __shfl_xor(aA0, off); r1 = __shfl_xor(aB0, off);
        mn = fminf(aA0, r0); aA0 = fmaxf(aA0, r0); aB0 = fmaxf(mn, fmaxf(aB0, r1));
        r0 = __shfl_xor(aA1, off); r1 = __shfl_xor(aB1, off);
        mn = fminf(aA1, r0); aA1 = fmaxf(aA1, r0); aB1 = fmaxf(mn, fmaxf(aB1, r1));
        m0 = fmaxf(m0, __shfl_xor(m0, off));
        m1 = fmaxf(m1, __shfl_xor(m1, off));
    }

    // recover global candidate indices (wave-uniform)
    const int jo0_0 = recover_j(oA0, soA0, soB0);
    const int jo1_0 = recover_j(oB0, soA0, soB0);
    const int jo0_1 = recover_j(oA1, soA1, soB1);
    const int jo1_1 = recover_j(oB1, soA1, soB1);
    const int ja0_0 = recover_j(aA0, saA0, saB0);
    const int ja1_0 = recover_j(aB0, saA0, saB0);
    const int ja0_1 = recover_j(aA1, saA1, saB1);
    const int ja1_1 = recover_j(aB1, saA1, saB1);
    const int jm_0  = recover_j(m0, sm0, sm0);
    const int jm_1  = recover_j(m1, sm1, sm1);

    float val = 0.0f;
    if (ch < 2) {                       // lane0 -> q0, lane1 -> q1
        const int q  = ch ? q1 : q0;
        const float4 qo = ob[q];        // reload from L2 (not kept live)
        const float4 qa = ab[q];
        const int io0 = ch ? jo0_1 : jo0_0;
        const int io1 = ch ? jo1_1 : jo1_0;
        const int ia0 = ch ? ja0_1 : ja0_0;
        const int ia1 = ch ? ja1_1 : ja1_0;
        const int im  = ch ? jm_1  : jm_0;

        const float nx = nb[3 * q], ny = nb[3 * q + 1], nz = nb[3 * q + 2];
        const float ok = 0.5f * (unit_absdot4(ob, io0, qo.x, qo.y, qo.z, nx, ny, nz) +
                                 unit_absdot4(ob, io1, qo.x, qo.y, qo.z, nx, ny, nz));
        const float ax = nb[3 * im], ay = nb[3 * im + 1], az = nb[3 * im + 2];
        const float ak = 0.5f * (unit_absdot4(ab, ia0, qa.x, qa.y, qa.z, ax, ay, az) +
                                 unit_absdot4(ab, ia1, qa.x, qa.y, qa.z, ax, ay, az));
        const float d = ak - ok;
        val = d * d;
    }
    val += __shfl_down(val, 1);         // lane0: q0 + q1

    __shared__ float sval[4];
    if (ch == 0) sval[qs] = val;
    __syncthreads();
    if (tid == 0) {
        const float s = sval[0] + sval[1] + sval[2] + sval[3];
        if (use_partial) partial[blockIdx.x] = s;
        else             atomicAdd(out, s * (1.0f / (float)(BB * NN)));
    }
}

__global__ __launch_bounds__(256) void reduce_kernel(
    const float* __restrict__ partial, float* __restrict__ out)
{
    const int tid = threadIdx.x;
    float s = 0.0f;
    #pragma unroll
    for (int i = tid; i < NBLK; i += 256) s += partial[i];
    #pragma unroll
    for (int off = 32; off > 0; off >>= 1) s += __shfl_down(s, off);
    __shared__ float ls[4];
    if ((tid & 63) == 0) ls[tid >> 6] = s;
    __syncthreads();
    if (tid == 0)
        out[0] = (ls[0] + ls[1] + ls[2] + ls[3]) * (1.0f / (float)(BB * NN));
}

extern "C" void kernel_launch(void* const* d_in, const int* in_sizes, int n_in,
                              void* d_out, int out_size, void* d_ws, size_t ws_size,
                              hipStream_t stream) {
    const float* ori = (const float*)d_in[0];
    const float* adv = (const float*)d_in[1];
    const float* nrm = (const float*)d_in[2];
    float* out = (float*)d_out;

    float4* oriP = (float4*)d_ws;                    // 256 KB
    float4* advP = oriP + (size_t)BB * NN;           // 256 KB
    float*  part = (float*)(advP + (size_t)BB * NN); // 8 KB
    const size_t need = (size_t)2 * BB * NN * sizeof(float4) + NBLK * sizeof(float);
    const int use_partial = (ws_size >= need) ? 1 : 0;

    if (!use_partial)
        hipMemsetAsync(out, 0, sizeof(float), stream);

    hipLaunchKernelGGL(pack_kernel, dim3((BB * NN + 255) / 256), dim3(256), 0, stream,
                       ori, adv, oriP, advP);
    hipLaunchKernelGGL(knn_kernel, dim3(NBLK), dim3(256), 0, stream,
                       oriP, advP, nrm, part, out, use_partial);
    if (use_partial)
        hipLaunchKernelGGL(reduce_kernel, dim3(1), dim3(256), 0, stream, part, out);
}